// Round 2
// baseline (883.597 us; speedup 1.0000x reference)
//
#include <hip/hip_runtime.h>
#include <hip/hip_bf16.h>
#include <cstdint>
#include <cstddef>

#define S_LEN 2048
#define NH 12
#define HD 64
#define EDIM 768
// exponent = -(D_INTRINSIC + BETA) = -3.5, BANDWIDTH^0.5 = 1

// ---------------------------------------------------------------------------
// Kernel 1: fused Q/V projection GEMM.  M=4096 (b*S+i), N=1536 (Q cols 0..767,
// V cols 768..1535), K=768.  Writes Q,V in [B*H, S, D] fp32 layout plus
// qn[b*H+h][i] = |q_i|^2 (computed in-register via shfl reduce).
// grid (24, 64), block 256.
// ---------------------------------------------------------------------------
__global__ __launch_bounds__(256) void qv_proj_kernel(
    const float* __restrict__ hs,
    const float* __restrict__ Wq, const float* __restrict__ bq,
    const float* __restrict__ Wv, const float* __restrict__ bv,
    float* __restrict__ Q, float* __restrict__ V, float* __restrict__ qn)
{
    __shared__ float As[16][68];   // [kk][m], padded
    __shared__ float Bs[16][68];   // [kk][n], padded

    const int t  = threadIdx.x;
    const int m0 = blockIdx.y << 6;
    const int c0 = blockIdx.x << 6;
    const bool isQ = (c0 < EDIM);
    const float* W    = isQ ? Wq : Wv;
    const float* bias = isQ ? bq : bv;
    const int cb = isQ ? c0 : (c0 - EDIM);

    const int tx = t & 15;
    const int ty = t >> 4;
    const int lm = t >> 2;          // 0..63
    const int lk = (t & 3) << 2;    // 0,4,8,12

    float acc[4][4];
#pragma unroll
    for (int r = 0; r < 4; r++)
#pragma unroll
        for (int c = 0; c < 4; c++) acc[r][c] = 0.f;

    for (int k0 = 0; k0 < EDIM; k0 += 16) {
        float4 a  = *(const float4*)(hs + (size_t)(m0 + lm) * EDIM + k0 + lk);
        float4 bb = *(const float4*)(W  + (size_t)(cb + lm) * EDIM + k0 + lk);
        __syncthreads();
        As[lk + 0][lm] = a.x;  As[lk + 1][lm] = a.y;
        As[lk + 2][lm] = a.z;  As[lk + 3][lm] = a.w;
        Bs[lk + 0][lm] = bb.x; Bs[lk + 1][lm] = bb.y;
        Bs[lk + 2][lm] = bb.z; Bs[lk + 3][lm] = bb.w;
        __syncthreads();
#pragma unroll
        for (int kk = 0; kk < 16; kk++) {
            float4 av  = *(const float4*)&As[kk][ty << 2];
            float4 bv4 = *(const float4*)&Bs[kk][tx << 2];
            acc[0][0] += av.x * bv4.x; acc[0][1] += av.x * bv4.y;
            acc[0][2] += av.x * bv4.z; acc[0][3] += av.x * bv4.w;
            acc[1][0] += av.y * bv4.x; acc[1][1] += av.y * bv4.y;
            acc[1][2] += av.y * bv4.z; acc[1][3] += av.y * bv4.w;
            acc[2][0] += av.z * bv4.x; acc[2][1] += av.z * bv4.y;
            acc[2][2] += av.z * bv4.z; acc[2][3] += av.z * bv4.w;
            acc[3][0] += av.w * bv4.x; acc[3][1] += av.w * bv4.y;
            acc[3][2] += av.w * bv4.z; acc[3][3] += av.w * bv4.w;
        }
    }

    const int h = cb >> 6;   // each 64-col tile is exactly one head
    float* outbase = isQ ? Q : V;
#pragma unroll
    for (int r = 0; r < 4; r++) {
        const int m = m0 + (ty << 2) + r;
        const int b = m >> 11;
        const int i = m & 2047;
        float v0 = acc[r][0] + bias[cb + (tx << 2) + 0];
        float v1 = acc[r][1] + bias[cb + (tx << 2) + 1];
        float v2 = acc[r][2] + bias[cb + (tx << 2) + 2];
        float v3 = acc[r][3] + bias[cb + (tx << 2) + 3];
        float* dst = outbase + (((size_t)(b * NH + h) * S_LEN + i) << 6) + (tx << 2);
        float4 o; o.x = v0; o.y = v1; o.z = v2; o.w = v3;
        *(float4*)dst = o;
        if (isQ) {
            float sq = v0 * v0 + v1 * v1 + v2 * v2 + v3 * v3;
            sq += __shfl_xor(sq, 1);
            sq += __shfl_xor(sq, 2);
            sq += __shfl_xor(sq, 4);
            sq += __shfl_xor(sq, 8);
            if (tx == 0) qn[(b * NH + h) * S_LEN + i] = sq;
        }
    }
}

// ---------------------------------------------------------------------------
// Kernel 2: distance attention, flash-style (no max needed: scores in (0,1]).
// One block = one (b,h) and 32 rows i.  Loop over 64 j-tiles of 32.
// grid (64, 24), block 256.  Thread t: row il=t>>3, dim-slice d0=(t&7)*8.
// Q-row cached in registers (64 floats) — reused across all 64 j-tiles.
// ---------------------------------------------------------------------------
__global__ __launch_bounds__(256) void attn_kernel(
    const float* __restrict__ Q, const float* __restrict__ V,
    const float* __restrict__ qn, const float* __restrict__ mask,
    float* __restrict__ AO)
{
    __shared__ float Qj[32][68];
    __shared__ float Vj[32][64];
    __shared__ float Wt[32][36];
    __shared__ float qnj[32], keepj[32];

    const int t  = threadIdx.x;
    const int bh = blockIdx.y;             // 0..23
    const int b  = bh / NH;
    const int i0 = blockIdx.x << 5;
    const float* Qb  = Q + ((size_t)bh << 17);    // bh * 2048 * 64
    const float* Vb  = V + ((size_t)bh << 17);
    const float* qnb = qn + (bh << 11);
    const float* mb  = mask + (b << 11);

    const int il = t >> 3;       // 0..31
    const int jg = t & 7;        // 0..7
    const int d0 = jg << 3;      // 0..56

    // register-cached Q row for this thread's i (8 threads share a row; L1 broadcast)
    float4 qr[16];
#pragma unroll
    for (int dq = 0; dq < 16; dq++)
        qr[dq] = *(const float4*)&Qb[((i0 + il) << 6) + (dq << 2)];
    const float qi_n = qnb[i0 + il];
    const float ki   = (mb[i0 + il] >= 0.f) ? 1.f : 0.f;

    float acc[8] = {0.f, 0.f, 0.f, 0.f, 0.f, 0.f, 0.f, 0.f};
    float wsum = 0.f;

    for (int j0 = 0; j0 < S_LEN; j0 += 32) {
        __syncthreads();   // previous tile's PV done before overwrite
#pragma unroll
        for (int u = 0; u < 2; u++) {
            int f = t + (u << 8);
            int r = f >> 4, c4 = (f & 15) << 2;
            *(float4*)&Qj[r][c4] = *(const float4*)&Qb[((j0 + r) << 6) + c4];
            *(float4*)&Vj[r][c4] = *(const float4*)&Vb[((j0 + r) << 6) + c4];
        }
        if (t < 32) {
            qnj[t]   = qnb[j0 + t];
            keepj[t] = (mb[j0 + t] >= 0.f) ? 1.f : 0.f;
        }
        __syncthreads();

        // --- scores: 4 per thread, j = jg + 8*s (conflict-free at stride 68)
        float dots[4] = {0.f, 0.f, 0.f, 0.f};
#pragma unroll
        for (int dq = 0; dq < 16; dq++) {
            float4 a = qr[dq];
#pragma unroll
            for (int s = 0; s < 4; s++) {
                float4 qb4 = *(const float4*)&Qj[jg + (s << 3)][dq << 2];
                dots[s] += a.x * qb4.x + a.y * qb4.y + a.z * qb4.z + a.w * qb4.w;
            }
        }
#pragma unroll
        for (int s = 0; s < 4; s++) {
            int jl = jg + (s << 3);
            float d2   = qi_n + qnj[jl] - 2.f * dots[s];
            float dist = sqrtf(fmaxf(d2, 1e-12f));
            dist = (ki * keepj[jl] != 0.f) ? dist : 2.0f;
            float score = exp2f(-3.5f * log2f(1.0f + dist));       // (1+d)^-3.5
            Wt[il][jl] = exp2f(score * 1.44269504088896341f);      // exp(score)
        }
        __syncthreads();

        // --- PV accumulation; every thread sums wsum over all j of its row
#pragma unroll
        for (int j = 0; j < 32; j++) {
            float w = Wt[il][j];
            wsum += w;
            float4 v0 = *(const float4*)&Vj[j][d0];
            float4 v1 = *(const float4*)&Vj[j][d0 + 4];
            acc[0] += w * v0.x; acc[1] += w * v0.y;
            acc[2] += w * v0.z; acc[3] += w * v0.w;
            acc[4] += w * v1.x; acc[5] += w * v1.y;
            acc[6] += w * v1.z; acc[7] += w * v1.w;
        }
    }

    float inv = 1.0f / wsum;
    const int h = bh - b * NH;
    float* dst = AO + (size_t)((b << 11) + i0 + il) * EDIM + (h << 6) + d0;
    float4 o0; o0.x = acc[0] * inv; o0.y = acc[1] * inv; o0.z = acc[2] * inv; o0.w = acc[3] * inv;
    float4 o1; o1.x = acc[4] * inv; o1.y = acc[5] * inv; o1.z = acc[6] * inv; o1.w = acc[7] * inv;
    *(float4*)dst = o0;
    *(float4*)(dst + 4) = o1;
}

// ---------------------------------------------------------------------------
// Kernel 3a: out-projection GEMM + bias + residual.  M=4096, N=768, K=768.
// TMP = AO @ Wo^T + bo + hs  (fp32).  grid (12, 64), block 256.
// ---------------------------------------------------------------------------
__global__ __launch_bounds__(256) void oproj_kernel(
    const float* __restrict__ AO, const float* __restrict__ Wo,
    const float* __restrict__ bo, const float* __restrict__ hs,
    float* __restrict__ TMP)
{
    __shared__ float As[16][68];
    __shared__ float Bs[16][68];

    const int t  = threadIdx.x;
    const int m0 = blockIdx.y << 6;
    const int c0 = blockIdx.x << 6;
    const int tx = t & 15;
    const int ty = t >> 4;
    const int lm = t >> 2;
    const int lk = (t & 3) << 2;

    float acc[4][4];
#pragma unroll
    for (int r = 0; r < 4; r++)
#pragma unroll
        for (int c = 0; c < 4; c++) acc[r][c] = 0.f;

    for (int k0 = 0; k0 < EDIM; k0 += 16) {
        float4 a  = *(const float4*)&AO[(size_t)(m0 + lm) * EDIM + k0 + lk];
        float4 bb = *(const float4*)&Wo[(size_t)(c0 + lm) * EDIM + k0 + lk];
        __syncthreads();
        As[lk + 0][lm] = a.x;  As[lk + 1][lm] = a.y;
        As[lk + 2][lm] = a.z;  As[lk + 3][lm] = a.w;
        Bs[lk + 0][lm] = bb.x; Bs[lk + 1][lm] = bb.y;
        Bs[lk + 2][lm] = bb.z; Bs[lk + 3][lm] = bb.w;
        __syncthreads();
#pragma unroll
        for (int kk = 0; kk < 16; kk++) {
            float4 av  = *(const float4*)&As[kk][ty << 2];
            float4 bv4 = *(const float4*)&Bs[kk][tx << 2];
            acc[0][0] += av.x * bv4.x; acc[0][1] += av.x * bv4.y;
            acc[0][2] += av.x * bv4.z; acc[0][3] += av.x * bv4.w;
            acc[1][0] += av.y * bv4.x; acc[1][1] += av.y * bv4.y;
            acc[1][2] += av.y * bv4.z; acc[1][3] += av.y * bv4.w;
            acc[2][0] += av.z * bv4.x; acc[2][1] += av.z * bv4.y;
            acc[2][2] += av.z * bv4.z; acc[2][3] += av.z * bv4.w;
            acc[3][0] += av.w * bv4.x; acc[3][1] += av.w * bv4.y;
            acc[3][2] += av.w * bv4.z; acc[3][3] += av.w * bv4.w;
        }
    }

#pragma unroll
    for (int r = 0; r < 4; r++) {
        const int m = m0 + (ty << 2) + r;
        float4 o;
        float* po = &o.x;
#pragma unroll
        for (int c = 0; c < 4; c++) {
            const int cg = c0 + (tx << 2) + c;
            po[c] = acc[r][c] + bo[cg] + hs[(size_t)m * EDIM + cg];
        }
        *(float4*)&TMP[(size_t)m * EDIM + c0 + (tx << 2)] = o;
    }
}

// ---------------------------------------------------------------------------
// Kernel 3b: LayerNorm over rows of TMP -> f32 output.  grid 4096, block 256.
// ---------------------------------------------------------------------------
__global__ __launch_bounds__(256) void ln_kernel(
    const float* __restrict__ X, const float* __restrict__ g,
    const float* __restrict__ be, float* __restrict__ out)
{
    const int row = blockIdx.x;
    const int t = threadIdx.x;
    const float* x = X + (size_t)row * EDIM;

    float s = 0.f, sq = 0.f;
#pragma unroll
    for (int c = t; c < EDIM; c += 256) {
        float v = x[c];
        s += v; sq += v * v;
    }
#pragma unroll
    for (int m = 1; m < 64; m <<= 1) {
        s  += __shfl_xor(s, m);
        sq += __shfl_xor(sq, m);
    }
    __shared__ float ss[4], ssq[4];
    const int w = t >> 6;
    if ((t & 63) == 0) { ss[w] = s; ssq[w] = sq; }
    __syncthreads();
    s  = ss[0] + ss[1] + ss[2] + ss[3];
    sq = ssq[0] + ssq[1] + ssq[2] + ssq[3];
    const float mu  = s * (1.f / EDIM);
    const float var = sq * (1.f / EDIM) - mu * mu;
    const float rstd = 1.0f / sqrtf(var + 1e-12f);

#pragma unroll
    for (int c = t; c < EDIM; c += 256) {
        out[(size_t)row * EDIM + c] = (x[c] - mu) * rstd * g[c] + be[c];
    }
}

// ---------------------------------------------------------------------------
extern "C" void kernel_launch(void* const* d_in, const int* in_sizes, int n_in,
                              void* d_out, int out_size, void* d_ws, size_t ws_size,
                              hipStream_t stream) {
    const float* hs   = (const float*)d_in[0];
    const float* mask = (const float*)d_in[1];
    const float* Wq   = (const float*)d_in[2];
    const float* bq   = (const float*)d_in[3];
    const float* Wv   = (const float*)d_in[4];
    const float* bv   = (const float*)d_in[5];
    const float* Wo   = (const float*)d_in[6];
    const float* bo   = (const float*)d_in[7];
    const float* g    = (const float*)d_in[8];
    const float* be   = (const float*)d_in[9];

    float* ws = (float*)d_ws;
    const size_t QV = (size_t)2 * NH * S_LEN * HD;   // 3,145,728 floats
    float* Q   = ws;
    float* V   = Q + QV;
    float* qn  = V + QV;                              // 49,152 floats
    float* AO  = qn + (size_t)2 * NH * S_LEN;
    float* TMP = Q;                                   // reuse (Q dead after attn)

    qv_proj_kernel<<<dim3(24, 64), 256, 0, stream>>>(hs, Wq, bq, Wv, bv, Q, V, qn);
    attn_kernel  <<<dim3(64, 24), 256, 0, stream>>>(Q, V, qn, mask, AO);
    oproj_kernel <<<dim3(12, 64), 256, 0, stream>>>(AO, Wo, bo, hs, TMP);
    ln_kernel    <<<dim3(4096),   256, 0, stream>>>(TMP, g, be, (float*)d_out);
}

// Round 3
// 467.055 us; speedup vs baseline: 1.8918x; 1.8918x over previous
//
#include <hip/hip_runtime.h>
#include <hip/hip_bf16.h>
#include <cstdint>
#include <cstddef>

#define S_LEN 2048
#define NH 12
#define HD 64
#define EDIM 768
// exponent = -(D_INTRINSIC + BETA) = -3.5, BANDWIDTH^0.5 = 1

typedef short bf16x8 __attribute__((ext_vector_type(8)));
typedef float f32x4  __attribute__((ext_vector_type(4)));

__device__ __forceinline__ unsigned short f2bf(float f) {
    return __bfloat16_as_ushort(__float2bfloat16(f));
}
__device__ __forceinline__ float bf2f(unsigned short u) {
    union { unsigned int i; float f; } x;
    x.i = ((unsigned int)u) << 16;
    return x.f;
}

// ---------------------------------------------------------------------------
// Kernel 1: fused Q/V projection GEMM (fp32 compute).  M=4096, N=1536
// (Q cols 0..767, V cols 768..1535), K=768.
// Outputs: Qb bf16 [bh][s][64], Vt bf16 [bh][d][s] (transposed!),
// qn fp32 [bh][s] computed from the bf16-ROUNDED q (diagonal consistency
// with the MFMA gram in attn).  grid (24,64), block 256.
// ---------------------------------------------------------------------------
__global__ __launch_bounds__(256) void qv_proj_kernel(
    const float* __restrict__ hs,
    const float* __restrict__ Wq, const float* __restrict__ bq,
    const float* __restrict__ Wv, const float* __restrict__ bv,
    unsigned short* __restrict__ Qb, unsigned short* __restrict__ Vt,
    float* __restrict__ qn)
{
    __shared__ float As[16][68];
    __shared__ float Bs[16][68];

    const int t  = threadIdx.x;
    const int m0 = blockIdx.y << 6;
    const int c0 = blockIdx.x << 6;
    const bool isQ = (c0 < EDIM);
    const float* W    = isQ ? Wq : Wv;
    const float* bias = isQ ? bq : bv;
    const int cb = isQ ? c0 : (c0 - EDIM);

    const int tx = t & 15;
    const int ty = t >> 4;
    const int lm = t >> 2;
    const int lk = (t & 3) << 2;

    float acc[4][4];
#pragma unroll
    for (int r = 0; r < 4; r++)
#pragma unroll
        for (int c = 0; c < 4; c++) acc[r][c] = 0.f;

    for (int k0 = 0; k0 < EDIM; k0 += 16) {
        float4 a  = *(const float4*)(hs + (size_t)(m0 + lm) * EDIM + k0 + lk);
        float4 bb = *(const float4*)(W  + (size_t)(cb + lm) * EDIM + k0 + lk);
        __syncthreads();
        As[lk + 0][lm] = a.x;  As[lk + 1][lm] = a.y;
        As[lk + 2][lm] = a.z;  As[lk + 3][lm] = a.w;
        Bs[lk + 0][lm] = bb.x; Bs[lk + 1][lm] = bb.y;
        Bs[lk + 2][lm] = bb.z; Bs[lk + 3][lm] = bb.w;
        __syncthreads();
#pragma unroll
        for (int kk = 0; kk < 16; kk++) {
            float4 av  = *(const float4*)&As[kk][ty << 2];
            float4 bv4 = *(const float4*)&Bs[kk][tx << 2];
            acc[0][0] += av.x * bv4.x; acc[0][1] += av.x * bv4.y;
            acc[0][2] += av.x * bv4.z; acc[0][3] += av.x * bv4.w;
            acc[1][0] += av.y * bv4.x; acc[1][1] += av.y * bv4.y;
            acc[1][2] += av.y * bv4.z; acc[1][3] += av.y * bv4.w;
            acc[2][0] += av.z * bv4.x; acc[2][1] += av.z * bv4.y;
            acc[2][2] += av.z * bv4.z; acc[2][3] += av.z * bv4.w;
            acc[3][0] += av.w * bv4.x; acc[3][1] += av.w * bv4.y;
            acc[3][2] += av.w * bv4.z; acc[3][3] += av.w * bv4.w;
        }
    }

    const int h = cb >> 6;
    if (isQ) {
#pragma unroll
        for (int r = 0; r < 4; r++) {
            const int m = m0 + (ty << 2) + r;
            const int b = m >> 11;
            const int i = m & 2047;
            unsigned short u0 = f2bf(acc[r][0] + bias[cb + (tx << 2) + 0]);
            unsigned short u1 = f2bf(acc[r][1] + bias[cb + (tx << 2) + 1]);
            unsigned short u2 = f2bf(acc[r][2] + bias[cb + (tx << 2) + 2]);
            unsigned short u3 = f2bf(acc[r][3] + bias[cb + (tx << 2) + 3]);
            ushort4 o; o.x = u0; o.y = u1; o.z = u2; o.w = u3;
            *(ushort4*)(Qb + ((size_t)(b * NH + h) * S_LEN + i) * HD + (tx << 2)) = o;
            float f0 = bf2f(u0), f1 = bf2f(u1), f2 = bf2f(u2), f3 = bf2f(u3);
            float sq = f0 * f0 + f1 * f1 + f2 * f2 + f3 * f3;
            sq += __shfl_xor(sq, 1);
            sq += __shfl_xor(sq, 2);
            sq += __shfl_xor(sq, 4);
            sq += __shfl_xor(sq, 8);
            if (tx == 0) qn[(b * NH + h) * S_LEN + i] = sq;
        }
    } else {
        // round all 16 first, then store transposed: 4 consecutive j per d
        unsigned short u[4][4];
#pragma unroll
        for (int r = 0; r < 4; r++)
#pragma unroll
            for (int c = 0; c < 4; c++)
                u[r][c] = f2bf(acc[r][c] + bias[cb + (tx << 2) + c]);
        const int m = m0 + (ty << 2);
        const int b = m >> 11;
        const int i = m & 2047;
#pragma unroll
        for (int c = 0; c < 4; c++) {
            ushort4 o; o.x = u[0][c]; o.y = u[1][c]; o.z = u[2][c]; o.w = u[3][c];
            *(ushort4*)(Vt + ((size_t)(b * NH + h) * HD + (tx << 2) + c) * S_LEN + i) = o;
        }
    }
}

// ---------------------------------------------------------------------------
// Kernel 2: MFMA distance attention.  Block = (b,h) x 64 i-rows, 4 waves.
// Wave w owns i-rows iw..iw+15.  Loop over j-tiles of 64.
//   QK:  S = Qi.Qj^T via mfma_f32_16x16x32_bf16 (A=Qi frags in regs, B from
//        global Qb — B-frag gather == A-frag gather for a gram matrix).
//   transform: d2 = qn_i + qn_j - 2 dot; w = exp((1+dist)^-3.5).
//   P round-trips LDS (per-wave-private strip) C-layout -> A-layout.
//   PV:  O += P.V via MFMA, B-frags contiguous from global Vt.
// No __syncthreads in the j-loop.  grid (32, 24), block 256.
// ---------------------------------------------------------------------------
__global__ __launch_bounds__(256) void attn_kernel(
    const unsigned short* __restrict__ Qb, const unsigned short* __restrict__ Vt,
    const float* __restrict__ qn, const float* __restrict__ mask,
    float* __restrict__ AO)
{
    __shared__ unsigned short Wt[4][16][72];   // per-wave P strip, 72: 16B-aligned rows

    const int t  = threadIdx.x;
    const int w  = t >> 6;
    const int l  = t & 63;
    const int ll = l & 15;
    const int lq = l >> 4;
    const int bh = blockIdx.y;
    const int b  = bh / NH;
    const int h  = bh - b * NH;
    const int i0 = blockIdx.x << 6;
    const int iw = i0 + (w << 4);

    const unsigned short* Qbase = Qb + ((size_t)bh << 17);  // 2048*64
    const unsigned short* Vbase = Vt + ((size_t)bh << 17);  // 64*2048
    const float* qnb = qn + (bh << 11);
    const float* mb  = mask + (b << 11);

    // A-frags of Qi: A[m=ll][k=lq*8+j], two frags for K=64.  Held all loop.
    bf16x8 aQ0 = *(const bf16x8*)(Qbase + (size_t)(iw + ll) * HD + (lq << 3));
    bf16x8 aQ1 = *(const bf16x8*)(Qbase + (size_t)(iw + ll) * HD + 32 + (lq << 3));

    // per-lane C-row constants: rows iw + lq*4 + r
    float qni[4], keepi[4];
#pragma unroll
    for (int r = 0; r < 4; r++) {
        int row = iw + (lq << 2) + r;
        qni[r]   = qnb[row];
        keepi[r] = (mb[row] >= 0.f) ? 1.f : 0.f;
    }

    f32x4 oacc[4];
#pragma unroll
    for (int m = 0; m < 4; m++) oacc[m] = (f32x4){0.f, 0.f, 0.f, 0.f};
    float wacc[4] = {0.f, 0.f, 0.f, 0.f};

    for (int j0 = 0; j0 < S_LEN; j0 += 64) {
        // ---- QK gram: 4 j-subtiles of 16
        f32x4 s[4];
#pragma unroll
        for (int n = 0; n < 4; n++) {
            const unsigned short* bp = Qbase + (size_t)(j0 + (n << 4) + ll) * HD + (lq << 3);
            bf16x8 b0 = *(const bf16x8*)(bp);
            bf16x8 b1 = *(const bf16x8*)(bp + 32);
            f32x4 c = (f32x4){0.f, 0.f, 0.f, 0.f};
            c = __builtin_amdgcn_mfma_f32_16x16x32_bf16(aQ0, b0, c, 0, 0, 0);
            c = __builtin_amdgcn_mfma_f32_16x16x32_bf16(aQ1, b1, c, 0, 0, 0);
            s[n] = c;
        }
        // ---- transform + write P strip (C layout: col=ll, row=lq*4+r)
#pragma unroll
        for (int n = 0; n < 4; n++) {
            int jc = j0 + (n << 4) + ll;
            float qnj = qnb[jc];
            float kj  = (mb[jc] >= 0.f) ? 1.f : 0.f;
#pragma unroll
            for (int r = 0; r < 4; r++) {
                float d2   = qni[r] + qnj - 2.f * s[n][r];
                float dist = __builtin_amdgcn_sqrtf(fmaxf(d2, 1e-12f));
                dist = (keepi[r] * kj != 0.f) ? dist : 2.0f;
                float p  = __builtin_exp2f(-3.5f * __builtin_log2f(1.0f + dist));
                float wv = __builtin_exp2f(1.44269504088896341f * p);  // exp(score)
                wacc[r] += wv;
                Wt[w][(lq << 2) + r][(n << 4) + ll] = f2bf(wv);
            }
        }
        __builtin_amdgcn_wave_barrier();   // order LDS writes before reads (same wave)
        // ---- P A-frags from LDS, V B-frags from global Vt, PV MFMA
        const unsigned short* wrow = &Wt[w][ll][0];
        bf16x8 aP0 = *(const bf16x8*)(wrow + (lq << 3));
        bf16x8 aP1 = *(const bf16x8*)(wrow + 32 + (lq << 3));
#pragma unroll
        for (int m = 0; m < 4; m++) {
            const unsigned short* vp = Vbase + (size_t)((m << 4) + ll) * S_LEN + j0 + (lq << 3);
            bf16x8 v0 = *(const bf16x8*)(vp);
            bf16x8 v1 = *(const bf16x8*)(vp + 32);
            oacc[m] = __builtin_amdgcn_mfma_f32_16x16x32_bf16(aP0, v0, oacc[m], 0, 0, 0);
            oacc[m] = __builtin_amdgcn_mfma_f32_16x16x32_bf16(aP1, v1, oacc[m], 0, 0, 0);
        }
        __builtin_amdgcn_wave_barrier();   // reads of this iter before next writes
    }

    // row sums: reduce wacc over the 16 j-lanes (low 4 lane bits)
#pragma unroll
    for (int r = 0; r < 4; r++) {
        wacc[r] += __shfl_xor(wacc[r], 1);
        wacc[r] += __shfl_xor(wacc[r], 2);
        wacc[r] += __shfl_xor(wacc[r], 4);
        wacc[r] += __shfl_xor(wacc[r], 8);
    }

#pragma unroll
    for (int r = 0; r < 4; r++) {
        float inv = 1.0f / wacc[r];
        int row = iw + (lq << 2) + r;
        float* dst = AO + (size_t)((b << 11) + row) * EDIM + (h << 6);
#pragma unroll
        for (int m = 0; m < 4; m++)
            dst[(m << 4) + ll] = oacc[m][r] * inv;
    }
}

// ---------------------------------------------------------------------------
// Kernel 3a: out-projection GEMM + bias + residual (fp32).  grid (12,64).
// ---------------------------------------------------------------------------
__global__ __launch_bounds__(256) void oproj_kernel(
    const float* __restrict__ AO, const float* __restrict__ Wo,
    const float* __restrict__ bo, const float* __restrict__ hs,
    float* __restrict__ TMP)
{
    __shared__ float As[16][68];
    __shared__ float Bs[16][68];

    const int t  = threadIdx.x;
    const int m0 = blockIdx.y << 6;
    const int c0 = blockIdx.x << 6;
    const int tx = t & 15;
    const int ty = t >> 4;
    const int lm = t >> 2;
    const int lk = (t & 3) << 2;

    float acc[4][4];
#pragma unroll
    for (int r = 0; r < 4; r++)
#pragma unroll
        for (int c = 0; c < 4; c++) acc[r][c] = 0.f;

    for (int k0 = 0; k0 < EDIM; k0 += 16) {
        float4 a  = *(const float4*)&AO[(size_t)(m0 + lm) * EDIM + k0 + lk];
        float4 bb = *(const float4*)&Wo[(size_t)(c0 + lm) * EDIM + k0 + lk];
        __syncthreads();
        As[lk + 0][lm] = a.x;  As[lk + 1][lm] = a.y;
        As[lk + 2][lm] = a.z;  As[lk + 3][lm] = a.w;
        Bs[lk + 0][lm] = bb.x; Bs[lk + 1][lm] = bb.y;
        Bs[lk + 2][lm] = bb.z; Bs[lk + 3][lm] = bb.w;
        __syncthreads();
#pragma unroll
        for (int kk = 0; kk < 16; kk++) {
            float4 av  = *(const float4*)&As[kk][ty << 2];
            float4 bv4 = *(const float4*)&Bs[kk][tx << 2];
            acc[0][0] += av.x * bv4.x; acc[0][1] += av.x * bv4.y;
            acc[0][2] += av.x * bv4.z; acc[0][3] += av.x * bv4.w;
            acc[1][0] += av.y * bv4.x; acc[1][1] += av.y * bv4.y;
            acc[1][2] += av.y * bv4.z; acc[1][3] += av.y * bv4.w;
            acc[2][0] += av.z * bv4.x; acc[2][1] += av.z * bv4.y;
            acc[2][2] += av.z * bv4.z; acc[2][3] += av.z * bv4.w;
            acc[3][0] += av.w * bv4.x; acc[3][1] += av.w * bv4.y;
            acc[3][2] += av.w * bv4.z; acc[3][3] += av.w * bv4.w;
        }
    }

#pragma unroll
    for (int r = 0; r < 4; r++) {
        const int m = m0 + (ty << 2) + r;
        float4 o;
        float* po = &o.x;
#pragma unroll
        for (int c = 0; c < 4; c++) {
            const int cg = c0 + (tx << 2) + c;
            po[c] = acc[r][c] + bo[cg] + hs[(size_t)m * EDIM + cg];
        }
        *(float4*)&TMP[(size_t)m * EDIM + c0 + (tx << 2)] = o;
    }
}

// ---------------------------------------------------------------------------
// Kernel 3b: LayerNorm -> f32 output.  grid 4096, block 256.
// ---------------------------------------------------------------------------
__global__ __launch_bounds__(256) void ln_kernel(
    const float* __restrict__ X, const float* __restrict__ g,
    const float* __restrict__ be, float* __restrict__ out)
{
    const int row = blockIdx.x;
    const int t = threadIdx.x;
    const float* x = X + (size_t)row * EDIM;

    float s = 0.f, sq = 0.f;
#pragma unroll
    for (int c = t; c < EDIM; c += 256) {
        float v = x[c];
        s += v; sq += v * v;
    }
#pragma unroll
    for (int m = 1; m < 64; m <<= 1) {
        s  += __shfl_xor(s, m);
        sq += __shfl_xor(sq, m);
    }
    __shared__ float ss[4], ssq[4];
    const int w = t >> 6;
    if ((t & 63) == 0) { ss[w] = s; ssq[w] = sq; }
    __syncthreads();
    s  = ss[0] + ss[1] + ss[2] + ss[3];
    sq = ssq[0] + ssq[1] + ssq[2] + ssq[3];
    const float mu  = s * (1.f / EDIM);
    const float var = sq * (1.f / EDIM) - mu * mu;
    const float rstd = 1.0f / sqrtf(var + 1e-12f);

#pragma unroll
    for (int c = t; c < EDIM; c += 256) {
        out[(size_t)row * EDIM + c] = (x[c] - mu) * rstd * g[c] + be[c];
    }
}

// ---------------------------------------------------------------------------
extern "C" void kernel_launch(void* const* d_in, const int* in_sizes, int n_in,
                              void* d_out, int out_size, void* d_ws, size_t ws_size,
                              hipStream_t stream) {
    const float* hs   = (const float*)d_in[0];
    const float* mask = (const float*)d_in[1];
    const float* Wq   = (const float*)d_in[2];
    const float* bq   = (const float*)d_in[3];
    const float* Wv   = (const float*)d_in[4];
    const float* bv   = (const float*)d_in[5];
    const float* Wo   = (const float*)d_in[6];
    const float* bo   = (const float*)d_in[7];
    const float* g    = (const float*)d_in[8];
    const float* be   = (const float*)d_in[9];

    char* w8 = (char*)d_ws;
    const size_t QVn = (size_t)2 * NH * S_LEN * HD;       // 3,145,728 elems
    unsigned short* Qb = (unsigned short*)w8;              // bf16, 6.29 MB
    unsigned short* Vt = Qb + QVn;                         // bf16, 6.29 MB
    float* qn  = (float*)(w8 + 2 * QVn * sizeof(unsigned short));
    float* AO  = qn + 2 * NH * S_LEN;                      // fp32, 12.6 MB
    float* TMP = (float*)w8;                               // alias Qb+Vt (dead)

    qv_proj_kernel<<<dim3(24, 64), 256, 0, stream>>>(hs, Wq, bq, Wv, bv, Qb, Vt, qn);
    attn_kernel  <<<dim3(32, 24), 256, 0, stream>>>(Qb, Vt, qn, mask, AO);
    oproj_kernel <<<dim3(12, 64), 256, 0, stream>>>(AO, Wo, bo, hs, TMP);
    ln_kernel    <<<dim3(4096),   256, 0, stream>>>(TMP, g, be, (float*)d_out);
}

// Round 4
// 373.949 us; speedup vs baseline: 2.3629x; 1.2490x over previous
//
#include <hip/hip_runtime.h>
#include <hip/hip_bf16.h>
#include <cstdint>
#include <cstddef>

#define S_LEN 2048
#define NH 12
#define HD 64
#define EDIM 768
// exponent = -(D_INTRINSIC + BETA) = -3.5, BANDWIDTH^0.5 = 1

typedef short bf16x8 __attribute__((ext_vector_type(8)));
typedef float f32x4  __attribute__((ext_vector_type(4)));

__device__ __forceinline__ unsigned short f2bf(float f) {
    return __bfloat16_as_ushort(__float2bfloat16(f));
}
__device__ __forceinline__ float bf2f(unsigned short u) {
    union { unsigned int i; float f; } x;
    x.i = ((unsigned int)u) << 16;
    return x.f;
}
__device__ __forceinline__ float rsq_f32(float x) {
#if __has_builtin(__builtin_amdgcn_rsqf)
    return __builtin_amdgcn_rsqf(x);
#else
    return __builtin_amdgcn_rcpf(__builtin_amdgcn_sqrtf(x));
#endif
}

// ---------------------------------------------------------------------------
// Kernel 1: Q/V projection, bf16 MFMA GEMM.  C = hs @ W^T + b.
// M=4096, N=1536 (Q cols 0..767 | V cols 768..1535), K=768.
// Block 128x128 (4 waves 2x2, wave-tile 64x64, 16x16x32 MFMA).
// fp32 inputs rounded to bf16 during LDS staging.
// Epilogue: Q -> Qb bf16 [bh][s][64] + qn fp32 (from ROUNDED q);
//           V -> Vt bf16 [bh][d][s] (transposed, ushort4 along s).
// grid (12, 32), block 256.
// ---------------------------------------------------------------------------
__global__ __launch_bounds__(256) void qv_gemm(
    const float* __restrict__ hs,
    const float* __restrict__ Wq, const float* __restrict__ bq,
    const float* __restrict__ Wv, const float* __restrict__ bv,
    unsigned short* __restrict__ Qb, unsigned short* __restrict__ Vt,
    float* __restrict__ qn)
{
    __shared__ unsigned short As[128][40];   // [row][k], 80B rows (16B aligned)
    __shared__ unsigned short Bs[128][40];

    const int t  = threadIdx.x;
    const int m0 = blockIdx.y << 7;
    const int c0 = blockIdx.x << 7;
    const bool isQ = (c0 < EDIM);
    const float* W    = isQ ? Wq : Wv;
    const float* bias = isQ ? bq : bv;
    const int cb = isQ ? c0 : (c0 - EDIM);

    const int w  = t >> 6;
    const int l  = t & 63;
    const int ll = l & 15;
    const int lq = l >> 4;
    const int wx = w & 1;
    const int wy = w >> 1;

    const int srow = t & 127;
    const int sk0  = (t >> 7) << 4;   // 0 / 16

    f32x4 acc[4][4];
#pragma unroll
    for (int m = 0; m < 4; m++)
#pragma unroll
        for (int n = 0; n < 4; n++) acc[m][n] = (f32x4){0.f, 0.f, 0.f, 0.f};

    for (int k0 = 0; k0 < EDIM; k0 += 32) {
        const float* ap = hs + (size_t)(m0 + srow) * EDIM + k0 + sk0;
        const float* bp = W  + (size_t)(cb + srow) * EDIM + k0 + sk0;
        float4 a0 = ((const float4*)ap)[0], a1 = ((const float4*)ap)[1];
        float4 a2 = ((const float4*)ap)[2], a3 = ((const float4*)ap)[3];
        float4 b0 = ((const float4*)bp)[0], b1 = ((const float4*)bp)[1];
        float4 b2 = ((const float4*)bp)[2], b3 = ((const float4*)bp)[3];
        __syncthreads();
        bf16x8 va0, va1, vb0, vb1;
        va0[0]=(short)f2bf(a0.x); va0[1]=(short)f2bf(a0.y); va0[2]=(short)f2bf(a0.z); va0[3]=(short)f2bf(a0.w);
        va0[4]=(short)f2bf(a1.x); va0[5]=(short)f2bf(a1.y); va0[6]=(short)f2bf(a1.z); va0[7]=(short)f2bf(a1.w);
        va1[0]=(short)f2bf(a2.x); va1[1]=(short)f2bf(a2.y); va1[2]=(short)f2bf(a2.z); va1[3]=(short)f2bf(a2.w);
        va1[4]=(short)f2bf(a3.x); va1[5]=(short)f2bf(a3.y); va1[6]=(short)f2bf(a3.z); va1[7]=(short)f2bf(a3.w);
        vb0[0]=(short)f2bf(b0.x); vb0[1]=(short)f2bf(b0.y); vb0[2]=(short)f2bf(b0.z); vb0[3]=(short)f2bf(b0.w);
        vb0[4]=(short)f2bf(b1.x); vb0[5]=(short)f2bf(b1.y); vb0[6]=(short)f2bf(b1.z); vb0[7]=(short)f2bf(b1.w);
        vb1[0]=(short)f2bf(b2.x); vb1[1]=(short)f2bf(b2.y); vb1[2]=(short)f2bf(b2.z); vb1[3]=(short)f2bf(b2.w);
        vb1[4]=(short)f2bf(b3.x); vb1[5]=(short)f2bf(b3.y); vb1[6]=(short)f2bf(b3.z); vb1[7]=(short)f2bf(b3.w);
        *(bf16x8*)&As[srow][sk0]     = va0;
        *(bf16x8*)&As[srow][sk0 + 8] = va1;
        *(bf16x8*)&Bs[srow][sk0]     = vb0;
        *(bf16x8*)&Bs[srow][sk0 + 8] = vb1;
        __syncthreads();
        bf16x8 aF[4], bF[4];
#pragma unroll
        for (int m = 0; m < 4; m++)
            aF[m] = *(const bf16x8*)&As[(wy << 6) + (m << 4) + ll][lq << 3];
#pragma unroll
        for (int n = 0; n < 4; n++)
            bF[n] = *(const bf16x8*)&Bs[(wx << 6) + (n << 4) + ll][lq << 3];
#pragma unroll
        for (int m = 0; m < 4; m++)
#pragma unroll
            for (int n = 0; n < 4; n++)
                acc[m][n] = __builtin_amdgcn_mfma_f32_16x16x32_bf16(aF[m], bF[n], acc[m][n], 0, 0, 0);
    }

    const int hcol0 = cb + (wx << 6);        // head-aligned (mult of 64)
    const int h = hcol0 >> 6;
    const int rowbase = m0 + (wy << 6);
    const int b = rowbase >> 11;
    const int sbase = rowbase & 2047;

    if (isQ) {
#pragma unroll
        for (int m = 0; m < 4; m++) {
#pragma unroll
            for (int r = 0; r < 4; r++) {
                const int si = sbase + (m << 4) + (lq << 2) + r;
                unsigned short* qrow = Qb + ((size_t)(b * NH + h) * S_LEN + si) * HD;
                float qsq = 0.f;
#pragma unroll
                for (int n = 0; n < 4; n++) {
                    unsigned short u = f2bf(acc[m][n][r] + bias[hcol0 + (n << 4) + ll]);
                    qrow[(n << 4) + ll] = u;
                    float f = bf2f(u);
                    qsq += f * f;
                }
                qsq += __shfl_xor(qsq, 1);
                qsq += __shfl_xor(qsq, 2);
                qsq += __shfl_xor(qsq, 4);
                qsq += __shfl_xor(qsq, 8);
                if (ll == 0) qn[(b * NH + h) * S_LEN + si] = qsq;
            }
        }
    } else {
#pragma unroll
        for (int m = 0; m < 4; m++) {
            const int si = sbase + (m << 4) + (lq << 2);
#pragma unroll
            for (int n = 0; n < 4; n++) {
                ushort4 o;
                o.x = f2bf(acc[m][n][0] + bias[hcol0 + (n << 4) + ll]);
                o.y = f2bf(acc[m][n][1] + bias[hcol0 + (n << 4) + ll]);
                o.z = f2bf(acc[m][n][2] + bias[hcol0 + (n << 4) + ll]);
                o.w = f2bf(acc[m][n][3] + bias[hcol0 + (n << 4) + ll]);
                *(ushort4*)&Vt[((size_t)(b * NH + h) * HD + (n << 4) + ll) * S_LEN + si] = o;
            }
        }
    }
}

// ---------------------------------------------------------------------------
// Kernel 2: MFMA distance attention, j-split across wave pairs.
// Block = (b,h) x 32 i-rows, 4 waves: wave w -> i-sub (w&1), j-half (w>>1).
// Each wave: 16 j-tiles of 64.  Transform: 2 trans ops/score
// (sqrt, rsq((1+d)^7)); exp via 4th-order Taylor (scores in (0,1]).
// Partials reduced through LDS; output AO in bf16.  grid (64, 24), block 256.
// ---------------------------------------------------------------------------
__global__ __launch_bounds__(256) void attn_kernel(
    const unsigned short* __restrict__ Qb, const unsigned short* __restrict__ Vt,
    const float* __restrict__ qn, const float* __restrict__ mask,
    unsigned short* __restrict__ AObf)
{
    __shared__ unsigned short Wt[4][16][72];
    __shared__ float Red[2][64][20];

    const int t  = threadIdx.x;
    const int w  = t >> 6;
    const int l  = t & 63;
    const int ll = l & 15;
    const int lq = l >> 4;
    const int bh = blockIdx.y;
    const int b  = bh / NH;
    const int h  = bh - b * NH;
    const int i0 = blockIdx.x << 5;
    const int iw = i0 + ((w & 1) << 4);
    const int jbase = (w >> 1) << 10;

    const unsigned short* Qbase = Qb + ((size_t)bh << 17);
    const unsigned short* Vbase = Vt + ((size_t)bh << 17);
    const float* qnb = qn + (bh << 11);
    const float* mb  = mask + (b << 11);

    bf16x8 aQ0 = *(const bf16x8*)(Qbase + (size_t)(iw + ll) * HD + (lq << 3));
    bf16x8 aQ1 = *(const bf16x8*)(Qbase + (size_t)(iw + ll) * HD + 32 + (lq << 3));

    float qni[4], keepi[4];
#pragma unroll
    for (int r = 0; r < 4; r++) {
        int row = iw + (lq << 2) + r;
        qni[r]   = qnb[row];
        keepi[r] = (mb[row] >= 0.f) ? 1.f : 0.f;
    }

    f32x4 oacc[4];
#pragma unroll
    for (int m = 0; m < 4; m++) oacc[m] = (f32x4){0.f, 0.f, 0.f, 0.f};
    float wacc[4] = {0.f, 0.f, 0.f, 0.f};

    for (int jt = 0; jt < 16; jt++) {
        const int j0 = jbase + (jt << 6);
        // ---- QK gram
        f32x4 s[4];
#pragma unroll
        for (int n = 0; n < 4; n++) {
            const unsigned short* bp = Qbase + (size_t)(j0 + (n << 4) + ll) * HD + (lq << 3);
            bf16x8 b0 = *(const bf16x8*)(bp);
            bf16x8 b1 = *(const bf16x8*)(bp + 32);
            f32x4 c = (f32x4){0.f, 0.f, 0.f, 0.f};
            c = __builtin_amdgcn_mfma_f32_16x16x32_bf16(aQ0, b0, c, 0, 0, 0);
            c = __builtin_amdgcn_mfma_f32_16x16x32_bf16(aQ1, b1, c, 0, 0, 0);
            s[n] = c;
        }
        // ---- transform (2 trans/score) + write P strip
#pragma unroll
        for (int n = 0; n < 4; n++) {
            int jc = j0 + (n << 4) + ll;
            float qnj = qnb[jc];
            float kj  = (mb[jc] >= 0.f) ? 1.f : 0.f;
#pragma unroll
            for (int r = 0; r < 4; r++) {
                float d2   = fmaf(-2.f, s[n][r], qni[r] + qnj);
                float dist = __builtin_amdgcn_sqrtf(fmaxf(d2, 1e-12f));
                dist = (keepi[r] * kj != 0.f) ? dist : 2.0f;
                float x  = 1.0f + dist;
                float x2 = x * x;
                float x4 = x2 * x2;
                float x7 = x4 * x2 * x;
                float p  = rsq_f32(x7);                       // (1+d)^-3.5
                // exp(p), p in (0,1]: 4th-order Taylor, max abs err 0.00995
                float wv = fmaf(fmaf(fmaf(fmaf(0.041666668f, p, 0.16666667f),
                                          p, 0.5f), p, 1.0f), p, 1.0f);
                wacc[r] += wv;
                Wt[w][(lq << 2) + r][(n << 4) + ll] = f2bf(wv);
            }
        }
        __builtin_amdgcn_wave_barrier();
        // ---- PV
        const unsigned short* wrow = &Wt[w][ll][0];
        bf16x8 aP0 = *(const bf16x8*)(wrow + (lq << 3));
        bf16x8 aP1 = *(const bf16x8*)(wrow + 32 + (lq << 3));
#pragma unroll
        for (int m = 0; m < 4; m++) {
            const unsigned short* vp = Vbase + (size_t)((m << 4) + ll) * S_LEN + j0 + (lq << 3);
            bf16x8 v0 = *(const bf16x8*)(vp);
            bf16x8 v1 = *(const bf16x8*)(vp + 32);
            oacc[m] = __builtin_amdgcn_mfma_f32_16x16x32_bf16(aP0, v0, oacc[m], 0, 0, 0);
            oacc[m] = __builtin_amdgcn_mfma_f32_16x16x32_bf16(aP1, v1, oacc[m], 0, 0, 0);
        }
        __builtin_amdgcn_wave_barrier();
    }

#pragma unroll
    for (int r = 0; r < 4; r++) {
        wacc[r] += __shfl_xor(wacc[r], 1);
        wacc[r] += __shfl_xor(wacc[r], 2);
        wacc[r] += __shfl_xor(wacc[r], 4);
        wacc[r] += __shfl_xor(wacc[r], 8);
    }

    if (w >= 2) {
        const int wi = w - 2;
#pragma unroll
        for (int m = 0; m < 4; m++)
            *(f32x4*)&Red[wi][l][m << 2] = oacc[m];
#pragma unroll
        for (int r = 0; r < 4; r++)
            Red[wi][l][16 + r] = wacc[r];
    }
    __syncthreads();
    if (w < 2) {
#pragma unroll
        for (int m = 0; m < 4; m++) {
            f32x4 o = *(const f32x4*)&Red[w][l][m << 2];
            oacc[m] += o;
        }
#pragma unroll
        for (int r = 0; r < 4; r++) {
            float ws = wacc[r] + Red[w][l][16 + r];
            float inv = 1.0f / ws;
            const int row = iw + (lq << 2) + r;
            unsigned short* dst = AObf + (size_t)((b << 11) + row) * EDIM + (h << 6);
#pragma unroll
            for (int m = 0; m < 4; m++)
                dst[(m << 4) + ll] = f2bf(oacc[m][r] * inv);
        }
    }
}

// ---------------------------------------------------------------------------
// Kernel 3a: out-projection bf16 MFMA GEMM + bias + residual (fp32 out).
// A = AObf bf16, B = Wo fp32 (rounded in staging).  M=4096, N=768, K=768.
// grid (6, 32), block 256.
// ---------------------------------------------------------------------------
__global__ __launch_bounds__(256) void oproj_gemm(
    const unsigned short* __restrict__ AObf, const float* __restrict__ Wo,
    const float* __restrict__ bo, const float* __restrict__ hs,
    float* __restrict__ TMP)
{
    __shared__ unsigned short As[128][40];
    __shared__ unsigned short Bs[128][40];

    const int t  = threadIdx.x;
    const int m0 = blockIdx.y << 7;
    const int c0 = blockIdx.x << 7;

    const int w  = t >> 6;
    const int l  = t & 63;
    const int ll = l & 15;
    const int lq = l >> 4;
    const int wx = w & 1;
    const int wy = w >> 1;

    const int srow = t & 127;
    const int sk0  = (t >> 7) << 4;

    f32x4 acc[4][4];
#pragma unroll
    for (int m = 0; m < 4; m++)
#pragma unroll
        for (int n = 0; n < 4; n++) acc[m][n] = (f32x4){0.f, 0.f, 0.f, 0.f};

    for (int k0 = 0; k0 < EDIM; k0 += 32) {
        const unsigned short* ap = AObf + (size_t)(m0 + srow) * EDIM + k0 + sk0;
        const float* bp = Wo + (size_t)(c0 + srow) * EDIM + k0 + sk0;
        bf16x8 va0 = *(const bf16x8*)(ap);
        bf16x8 va1 = *(const bf16x8*)(ap + 8);
        float4 b0 = ((const float4*)bp)[0], b1 = ((const float4*)bp)[1];
        float4 b2 = ((const float4*)bp)[2], b3 = ((const float4*)bp)[3];
        __syncthreads();
        bf16x8 vb0, vb1;
        vb0[0]=(short)f2bf(b0.x); vb0[1]=(short)f2bf(b0.y); vb0[2]=(short)f2bf(b0.z); vb0[3]=(short)f2bf(b0.w);
        vb0[4]=(short)f2bf(b1.x); vb0[5]=(short)f2bf(b1.y); vb0[6]=(short)f2bf(b1.z); vb0[7]=(short)f2bf(b1.w);
        vb1[0]=(short)f2bf(b2.x); vb1[1]=(short)f2bf(b2.y); vb1[2]=(short)f2bf(b2.z); vb1[3]=(short)f2bf(b2.w);
        vb1[4]=(short)f2bf(b3.x); vb1[5]=(short)f2bf(b3.y); vb1[6]=(short)f2bf(b3.z); vb1[7]=(short)f2bf(b3.w);
        *(bf16x8*)&As[srow][sk0]     = va0;
        *(bf16x8*)&As[srow][sk0 + 8] = va1;
        *(bf16x8*)&Bs[srow][sk0]     = vb0;
        *(bf16x8*)&Bs[srow][sk0 + 8] = vb1;
        __syncthreads();
        bf16x8 aF[4], bF[4];
#pragma unroll
        for (int m = 0; m < 4; m++)
            aF[m] = *(const bf16x8*)&As[(wy << 6) + (m << 4) + ll][lq << 3];
#pragma unroll
        for (int n = 0; n < 4; n++)
            bF[n] = *(const bf16x8*)&Bs[(wx << 6) + (n << 4) + ll][lq << 3];
#pragma unroll
        for (int m = 0; m < 4; m++)
#pragma unroll
            for (int n = 0; n < 4; n++)
                acc[m][n] = __builtin_amdgcn_mfma_f32_16x16x32_bf16(aF[m], bF[n], acc[m][n], 0, 0, 0);
    }

#pragma unroll
    for (int m = 0; m < 4; m++) {
#pragma unroll
        for (int r = 0; r < 4; r++) {
            const int row = m0 + (wy << 6) + (m << 4) + (lq << 2) + r;
#pragma unroll
            for (int n = 0; n < 4; n++) {
                const int col = c0 + (wx << 6) + (n << 4) + ll;
                TMP[(size_t)row * EDIM + col] =
                    acc[m][n][r] + bo[col] + hs[(size_t)row * EDIM + col];
            }
        }
    }
}

// ---------------------------------------------------------------------------
// Kernel 3b: LayerNorm -> f32 output.  grid 4096, block 256.
// ---------------------------------------------------------------------------
__global__ __launch_bounds__(256) void ln_kernel(
    const float* __restrict__ X, const float* __restrict__ g,
    const float* __restrict__ be, float* __restrict__ out)
{
    const int row = blockIdx.x;
    const int t = threadIdx.x;
    const float* x = X + (size_t)row * EDIM;

    float s = 0.f, sq = 0.f;
#pragma unroll
    for (int c = t; c < EDIM; c += 256) {
        float v = x[c];
        s += v; sq += v * v;
    }
#pragma unroll
    for (int m = 1; m < 64; m <<= 1) {
        s  += __shfl_xor(s, m);
        sq += __shfl_xor(sq, m);
    }
    __shared__ float ss[4], ssq[4];
    const int w = t >> 6;
    if ((t & 63) == 0) { ss[w] = s; ssq[w] = sq; }
    __syncthreads();
    s  = ss[0] + ss[1] + ss[2] + ss[3];
    sq = ssq[0] + ssq[1] + ssq[2] + ssq[3];
    const float mu  = s * (1.f / EDIM);
    const float var = sq * (1.f / EDIM) - mu * mu;
    const float rstd = 1.0f / sqrtf(var + 1e-12f);

#pragma unroll
    for (int c = t; c < EDIM; c += 256) {
        out[(size_t)row * EDIM + c] = (x[c] - mu) * rstd * g[c] + be[c];
    }
}

// ---------------------------------------------------------------------------
extern "C" void kernel_launch(void* const* d_in, const int* in_sizes, int n_in,
                              void* d_out, int out_size, void* d_ws, size_t ws_size,
                              hipStream_t stream) {
    const float* hs   = (const float*)d_in[0];
    const float* mask = (const float*)d_in[1];
    const float* Wq   = (const float*)d_in[2];
    const float* bq   = (const float*)d_in[3];
    const float* Wv   = (const float*)d_in[4];
    const float* bv   = (const float*)d_in[5];
    const float* Wo   = (const float*)d_in[6];
    const float* bo   = (const float*)d_in[7];
    const float* g    = (const float*)d_in[8];
    const float* be   = (const float*)d_in[9];

    char* w8 = (char*)d_ws;
    const size_t QVn = (size_t)2 * NH * S_LEN * HD;          // 3,145,728 elems
    unsigned short* Qb   = (unsigned short*)w8;               // 6.29 MB
    unsigned short* Vt   = Qb + QVn;                          // 6.29 MB
    float*          qn   = (float*)(w8 + 2 * QVn * 2);        // 196 KB
    unsigned short* AObf = (unsigned short*)(qn + 2 * NH * S_LEN);  // 6.29 MB
    float*          TMP  = (float*)(AObf + QVn);              // 12.6 MB

    qv_gemm   <<<dim3(12, 32), 256, 0, stream>>>(hs, Wq, bq, Wv, bv, Qb, Vt, qn);
    attn_kernel<<<dim3(64, 24), 256, 0, stream>>>(Qb, Vt, qn, mask, AObf);
    oproj_gemm<<<dim3(6, 32),  256, 0, stream>>>(AObf, Wo, bo, hs, TMP);
    ln_kernel <<<dim3(4096),   256, 0, stream>>>(TMP, g, be, (float*)d_out);
}

// Round 5
// 336.143 us; speedup vs baseline: 2.6286x; 1.1125x over previous
//
#include <hip/hip_runtime.h>
#include <hip/hip_bf16.h>
#include <cstdint>
#include <cstddef>

#define S_LEN 2048
#define NH 12
#define HD 64
#define EDIM 768
// exponent = -(D_INTRINSIC + BETA) = -3.5, BANDWIDTH^0.5 = 1

typedef short bf16x8 __attribute__((ext_vector_type(8)));
typedef float f32x4  __attribute__((ext_vector_type(4)));

__device__ __forceinline__ unsigned short f2bf(float f) {
    return __bfloat16_as_ushort(__float2bfloat16(f));
}
__device__ __forceinline__ float bf2f(unsigned short u) {
    union { unsigned int i; float f; } x;
    x.i = ((unsigned int)u) << 16;
    return x.f;
}
__device__ __forceinline__ float rsq_f32(float x) {
#if __has_builtin(__builtin_amdgcn_rsqf)
    return __builtin_amdgcn_rsqf(x);
#else
    return __builtin_amdgcn_rcpf(__builtin_amdgcn_sqrtf(x));
#endif
}

// ---------------------------------------------------------------------------
// Kernel 0: one-shot fp32 -> bf16 pre-cast of hs, Wq|Wv (concatenated), Wo.
// One float4 -> ushort4 per thread.  grid 4800, block 256.
// Region boundaries in float4 units: hs 786432 | Wq 147456 | Wv 147456 | Wo 147456.
// ---------------------------------------------------------------------------
__global__ __launch_bounds__(256) void precast_kernel(
    const float* __restrict__ hs, const float* __restrict__ Wq,
    const float* __restrict__ Wv, const float* __restrict__ Wo,
    unsigned short* __restrict__ hsb, unsigned short* __restrict__ Wqvb,
    unsigned short* __restrict__ Wob)
{
    const int i4 = blockIdx.x * 256 + threadIdx.x;   // 0..1228799
    const float* src;
    unsigned short* dst;
    int rel;
    if (i4 < 786432)        { src = hs; dst = hsb;            rel = i4; }
    else if (i4 < 933888)   { src = Wq; dst = Wqvb;           rel = i4 - 786432; }
    else if (i4 < 1081344)  { src = Wv; dst = Wqvb + 589824;  rel = i4 - 933888; }
    else                    { src = Wo; dst = Wob;            rel = i4 - 1081344; }
    float4 v = ((const float4*)src)[rel];
    ushort4 o;
    o.x = f2bf(v.x); o.y = f2bf(v.y); o.z = f2bf(v.z); o.w = f2bf(v.w);
    ((ushort4*)dst)[rel] = o;
}

// ---------------------------------------------------------------------------
// Kernel 1: Q/V projection, bf16 MFMA GEMM from pre-cast inputs.
// C = hsb @ Wqvb^T + b.  M=4096, N=1536, K=768.  Block 128x128, 4 waves.
// Epilogue: Q -> Qb bf16 [bh][s][64] + qn fp32 (from rounded q);
//           V -> Vt bf16 [bh][d][s].  grid (12, 32), block 256.
// ---------------------------------------------------------------------------
__global__ __launch_bounds__(256) void qv_gemm(
    const unsigned short* __restrict__ hsb, const unsigned short* __restrict__ Wqvb,
    const float* __restrict__ bq, const float* __restrict__ bv,
    unsigned short* __restrict__ Qb, unsigned short* __restrict__ Vt,
    float* __restrict__ qn)
{
    __shared__ __align__(16) unsigned short As[128][40];
    __shared__ __align__(16) unsigned short Bs[128][40];

    const int t  = threadIdx.x;
    const int m0 = blockIdx.y << 7;
    const int c0 = blockIdx.x << 7;
    const bool isQ = (c0 < EDIM);
    const float* bias = isQ ? bq : bv;
    const int cb = isQ ? c0 : (c0 - EDIM);

    const int w  = t >> 6;
    const int l  = t & 63;
    const int ll = l & 15;
    const int lq = l >> 4;
    const int wx = w & 1;
    const int wy = w >> 1;

    const int srow = t & 127;
    const int sk0  = (t >> 7) << 4;   // 0 / 16

    f32x4 acc[4][4];
#pragma unroll
    for (int m = 0; m < 4; m++)
#pragma unroll
        for (int n = 0; n < 4; n++) acc[m][n] = (f32x4){0.f, 0.f, 0.f, 0.f};

    for (int k0 = 0; k0 < EDIM; k0 += 32) {
        const unsigned short* ap = hsb  + (size_t)(m0 + srow) * EDIM + k0 + sk0;
        const unsigned short* bp = Wqvb + (size_t)(c0 + srow) * EDIM + k0 + sk0;
        bf16x8 va0 = *(const bf16x8*)(ap);
        bf16x8 va1 = *(const bf16x8*)(ap + 8);
        bf16x8 vb0 = *(const bf16x8*)(bp);
        bf16x8 vb1 = *(const bf16x8*)(bp + 8);
        __syncthreads();
        *(bf16x8*)&As[srow][sk0]     = va0;
        *(bf16x8*)&As[srow][sk0 + 8] = va1;
        *(bf16x8*)&Bs[srow][sk0]     = vb0;
        *(bf16x8*)&Bs[srow][sk0 + 8] = vb1;
        __syncthreads();
        bf16x8 aF[4], bF[4];
#pragma unroll
        for (int m = 0; m < 4; m++)
            aF[m] = *(const bf16x8*)&As[(wy << 6) + (m << 4) + ll][lq << 3];
#pragma unroll
        for (int n = 0; n < 4; n++)
            bF[n] = *(const bf16x8*)&Bs[(wx << 6) + (n << 4) + ll][lq << 3];
#pragma unroll
        for (int m = 0; m < 4; m++)
#pragma unroll
            for (int n = 0; n < 4; n++)
                acc[m][n] = __builtin_amdgcn_mfma_f32_16x16x32_bf16(aF[m], bF[n], acc[m][n], 0, 0, 0);
    }

    const int hcol0 = cb + (wx << 6);        // head-aligned (mult of 64)
    const int h = hcol0 >> 6;
    const int rowbase = m0 + (wy << 6);
    const int b = rowbase >> 11;
    const int sbase = rowbase & 2047;

    if (isQ) {
#pragma unroll
        for (int m = 0; m < 4; m++) {
#pragma unroll
            for (int r = 0; r < 4; r++) {
                const int si = sbase + (m << 4) + (lq << 2) + r;
                unsigned short* qrow = Qb + ((size_t)(b * NH + h) * S_LEN + si) * HD;
                float qsq = 0.f;
#pragma unroll
                for (int n = 0; n < 4; n++) {
                    unsigned short u = f2bf(acc[m][n][r] + bias[hcol0 + (n << 4) + ll]);
                    qrow[(n << 4) + ll] = u;
                    float f = bf2f(u);
                    qsq += f * f;
                }
                qsq += __shfl_xor(qsq, 1);
                qsq += __shfl_xor(qsq, 2);
                qsq += __shfl_xor(qsq, 4);
                qsq += __shfl_xor(qsq, 8);
                if (ll == 0) qn[(b * NH + h) * S_LEN + si] = qsq;
            }
        }
    } else {
#pragma unroll
        for (int m = 0; m < 4; m++) {
            const int si = sbase + (m << 4) + (lq << 2);
#pragma unroll
            for (int n = 0; n < 4; n++) {
                ushort4 o;
                o.x = f2bf(acc[m][n][0] + bias[hcol0 + (n << 4) + ll]);
                o.y = f2bf(acc[m][n][1] + bias[hcol0 + (n << 4) + ll]);
                o.z = f2bf(acc[m][n][2] + bias[hcol0 + (n << 4) + ll]);
                o.w = f2bf(acc[m][n][3] + bias[hcol0 + (n << 4) + ll]);
                *(ushort4*)&Vt[((size_t)(b * NH + h) * HD + (n << 4) + ll) * S_LEN + si] = o;
            }
        }
    }
}

// ---------------------------------------------------------------------------
// Kernel 2: MFMA distance attention, software-pipelined.
// Block = (b,h) x 32 i-rows, 4 waves: wave w -> i-sub (w&1), j-half (w>>1).
// Per j-tile of 64: V-frags + qn/mask issued at top; gram B-frags double-
// buffered in regs (prefetch jt+1 right after gram consumes jt); single
// wave_barrier between P-strip write and read.  grid (64, 24), block 256.
// ---------------------------------------------------------------------------
__global__ __launch_bounds__(256) void attn_kernel(
    const unsigned short* __restrict__ Qb, const unsigned short* __restrict__ Vt,
    const float* __restrict__ qn, const float* __restrict__ mask,
    unsigned short* __restrict__ AObf)
{
    __shared__ __align__(16) unsigned short Wt[4][16][72];
    __shared__ __align__(16) float Red[2][64][20];

    const int t  = threadIdx.x;
    const int w  = t >> 6;
    const int l  = t & 63;
    const int ll = l & 15;
    const int lq = l >> 4;
    const int bh = blockIdx.y;
    const int b  = bh / NH;
    const int h  = bh - b * NH;
    const int i0 = blockIdx.x << 5;
    const int iw = i0 + ((w & 1) << 4);
    const int jbase = (w >> 1) << 10;

    const unsigned short* Qbase = Qb + ((size_t)bh << 17);
    const unsigned short* Vbase = Vt + ((size_t)bh << 17);
    const float* qnb = qn + (bh << 11);
    const float* mb  = mask + (b << 11);

    bf16x8 aQ0 = *(const bf16x8*)(Qbase + (size_t)(iw + ll) * HD + (lq << 3));
    bf16x8 aQ1 = *(const bf16x8*)(Qbase + (size_t)(iw + ll) * HD + 32 + (lq << 3));

    float qni[4], keepi[4];
#pragma unroll
    for (int r = 0; r < 4; r++) {
        int row = iw + (lq << 2) + r;
        qni[r]   = qnb[row];
        keepi[r] = (mb[row] >= 0.f) ? 1.f : 0.f;
    }

    f32x4 oacc[4];
#pragma unroll
    for (int m = 0; m < 4; m++) oacc[m] = (f32x4){0.f, 0.f, 0.f, 0.f};
    float wacc[4] = {0.f, 0.f, 0.f, 0.f};

    // prefetch gram B-frags for the first tile
    bf16x8 nb0[4], nb1[4];
#pragma unroll
    for (int n = 0; n < 4; n++) {
        const unsigned short* bp = Qbase + (size_t)(jbase + (n << 4) + ll) * HD + (lq << 3);
        nb0[n] = *(const bf16x8*)bp;
        nb1[n] = *(const bf16x8*)(bp + 32);
    }

#pragma unroll 2
    for (int jt = 0; jt < 16; jt++) {
        const int j0 = jbase + (jt << 6);
        const int jn = jbase + (((jt + 1) & 15) << 6);

        // per-tile row data (issued early; consumed after gram)
        float qnjv[4], kjf[4];
#pragma unroll
        for (int n = 0; n < 4; n++) {
            int jc = j0 + (n << 4) + ll;
            qnjv[n] = qnb[jc];
            kjf[n]  = (mb[jc] >= 0.f) ? 1.f : 0.f;
        }
        // V-frags for CURRENT tile (issued early; consumed after transform)
        bf16x8 v0[4], v1[4];
#pragma unroll
        for (int m = 0; m < 4; m++) {
            const unsigned short* vp = Vbase + (size_t)((m << 4) + ll) * S_LEN + j0 + (lq << 3);
            v0[m] = *(const bf16x8*)vp;
            v1[m] = *(const bf16x8*)(vp + 32);
        }
        // ---- gram with current B-frags
        f32x4 s[4];
#pragma unroll
        for (int n = 0; n < 4; n++) {
            f32x4 c = (f32x4){0.f, 0.f, 0.f, 0.f};
            c = __builtin_amdgcn_mfma_f32_16x16x32_bf16(aQ0, nb0[n], c, 0, 0, 0);
            c = __builtin_amdgcn_mfma_f32_16x16x32_bf16(aQ1, nb1[n], c, 0, 0, 0);
            s[n] = c;
        }
        // ---- prefetch NEXT tile's B-frags (covered by transform + PV)
#pragma unroll
        for (int n = 0; n < 4; n++) {
            const unsigned short* bp = Qbase + (size_t)(jn + (n << 4) + ll) * HD + (lq << 3);
            nb0[n] = *(const bf16x8*)bp;
            nb1[n] = *(const bf16x8*)(bp + 32);
        }
        // ---- transform (2 trans ops/score), cheap bf16 pack
#pragma unroll
        for (int n = 0; n < 4; n++) {
#pragma unroll
            for (int r = 0; r < 4; r++) {
                float d2   = fmaf(-2.f, s[n][r], qni[r] + qnjv[n]);
                float dist = __builtin_amdgcn_sqrtf(fmaxf(d2, 1e-12f));
                float ok   = keepi[r] * kjf[n];
                dist = (ok != 0.f) ? dist : 2.0f;
                float x  = 1.0f + dist;
                float x2 = x * x;
                float x4 = x2 * x2;
                float x7 = x4 * x2 * x;
                float p  = rsq_f32(x7);                       // (1+d)^-3.5
                // exp(p), p in (0,1]: 4th-order Taylor, max abs err 0.00995
                float wv = fmaf(fmaf(fmaf(fmaf(0.041666668f, p, 0.16666667f),
                                          p, 0.5f), p, 1.0f), p, 1.0f);
                wacc[r] += wv;
                union { float f; unsigned int u; } cv; cv.f = wv;
                Wt[w][(lq << 2) + r][(n << 4) + ll] =
                    (unsigned short)((cv.u + 0x8000u) >> 16);
            }
        }
        __builtin_amdgcn_wave_barrier();   // order strip writes before reads
        const unsigned short* wrow = &Wt[w][ll][0];
        bf16x8 aP0 = *(const bf16x8*)(wrow + (lq << 3));
        bf16x8 aP1 = *(const bf16x8*)(wrow + 32 + (lq << 3));
#pragma unroll
        for (int m = 0; m < 4; m++) {
            oacc[m] = __builtin_amdgcn_mfma_f32_16x16x32_bf16(aP0, v0[m], oacc[m], 0, 0, 0);
            oacc[m] = __builtin_amdgcn_mfma_f32_16x16x32_bf16(aP1, v1[m], oacc[m], 0, 0, 0);
        }
    }

#pragma unroll
    for (int r = 0; r < 4; r++) {
        wacc[r] += __shfl_xor(wacc[r], 1);
        wacc[r] += __shfl_xor(wacc[r], 2);
        wacc[r] += __shfl_xor(wacc[r], 4);
        wacc[r] += __shfl_xor(wacc[r], 8);
    }

    if (w >= 2) {
        const int wi = w - 2;
#pragma unroll
        for (int m = 0; m < 4; m++)
            *(f32x4*)&Red[wi][l][m << 2] = oacc[m];
#pragma unroll
        for (int r = 0; r < 4; r++)
            Red[wi][l][16 + r] = wacc[r];
    }
    __syncthreads();
    if (w < 2) {
#pragma unroll
        for (int m = 0; m < 4; m++) {
            f32x4 o = *(const f32x4*)&Red[w][l][m << 2];
            oacc[m] += o;
        }
#pragma unroll
        for (int r = 0; r < 4; r++) {
            float ws = wacc[r] + Red[w][l][16 + r];
            float inv = 1.0f / ws;
            const int row = iw + (lq << 2) + r;
            unsigned short* dst = AObf + (size_t)((b << 11) + row) * EDIM + (h << 6);
#pragma unroll
            for (int m = 0; m < 4; m++)
                dst[(m << 4) + ll] = f2bf(oacc[m][r] * inv);
        }
    }
}

// ---------------------------------------------------------------------------
// Kernel 3a: out-projection bf16 MFMA GEMM + bias + residual (fp32 out).
// A = AObf bf16, B = Wob bf16 (pre-cast).  M=4096, N=768, K=768.
// grid (6, 32), block 256.
// ---------------------------------------------------------------------------
__global__ __launch_bounds__(256) void oproj_gemm(
    const unsigned short* __restrict__ AObf, const unsigned short* __restrict__ Wob,
    const float* __restrict__ bo, const float* __restrict__ hs,
    float* __restrict__ TMP)
{
    __shared__ __align__(16) unsigned short As[128][40];
    __shared__ __align__(16) unsigned short Bs[128][40];

    const int t  = threadIdx.x;
    const int m0 = blockIdx.y << 7;
    const int c0 = blockIdx.x << 7;

    const int w  = t >> 6;
    const int l  = t & 63;
    const int ll = l & 15;
    const int lq = l >> 4;
    const int wx = w & 1;
    const int wy = w >> 1;

    const int srow = t & 127;
    const int sk0  = (t >> 7) << 4;

    f32x4 acc[4][4];
#pragma unroll
    for (int m = 0; m < 4; m++)
#pragma unroll
        for (int n = 0; n < 4; n++) acc[m][n] = (f32x4){0.f, 0.f, 0.f, 0.f};

    for (int k0 = 0; k0 < EDIM; k0 += 32) {
        const unsigned short* ap = AObf + (size_t)(m0 + srow) * EDIM + k0 + sk0;
        const unsigned short* bp = Wob  + (size_t)(c0 + srow) * EDIM + k0 + sk0;
        bf16x8 va0 = *(const bf16x8*)(ap);
        bf16x8 va1 = *(const bf16x8*)(ap + 8);
        bf16x8 vb0 = *(const bf16x8*)(bp);
        bf16x8 vb1 = *(const bf16x8*)(bp + 8);
        __syncthreads();
        *(bf16x8*)&As[srow][sk0]     = va0;
        *(bf16x8*)&As[srow][sk0 + 8] = va1;
        *(bf16x8*)&Bs[srow][sk0]     = vb0;
        *(bf16x8*)&Bs[srow][sk0 + 8] = vb1;
        __syncthreads();
        bf16x8 aF[4], bF[4];
#pragma unroll
        for (int m = 0; m < 4; m++)
            aF[m] = *(const bf16x8*)&As[(wy << 6) + (m << 4) + ll][lq << 3];
#pragma unroll
        for (int n = 0; n < 4; n++)
            bF[n] = *(const bf16x8*)&Bs[(wx << 6) + (n << 4) + ll][lq << 3];
#pragma unroll
        for (int m = 0; m < 4; m++)
#pragma unroll
            for (int n = 0; n < 4; n++)
                acc[m][n] = __builtin_amdgcn_mfma_f32_16x16x32_bf16(aF[m], bF[n], acc[m][n], 0, 0, 0);
    }

#pragma unroll
    for (int m = 0; m < 4; m++) {
#pragma unroll
        for (int r = 0; r < 4; r++) {
            const int row = m0 + (wy << 6) + (m << 4) + (lq << 2) + r;
#pragma unroll
            for (int n = 0; n < 4; n++) {
                const int col = c0 + (wx << 6) + (n << 4) + ll;
                TMP[(size_t)row * EDIM + col] =
                    acc[m][n][r] + bo[col] + hs[(size_t)row * EDIM + col];
            }
        }
    }
}

// ---------------------------------------------------------------------------
// Kernel 3b: LayerNorm -> f32 output.  grid 4096, block 256.
// ---------------------------------------------------------------------------
__global__ __launch_bounds__(256) void ln_kernel(
    const float* __restrict__ X, const float* __restrict__ g,
    const float* __restrict__ be, float* __restrict__ out)
{
    const int row = blockIdx.x;
    const int t = threadIdx.x;
    const float* x = X + (size_t)row * EDIM;

    float s = 0.f, sq = 0.f;
#pragma unroll
    for (int c = t; c < EDIM; c += 256) {
        float v = x[c];
        s += v; sq += v * v;
    }
#pragma unroll
    for (int m = 1; m < 64; m <<= 1) {
        s  += __shfl_xor(s, m);
        sq += __shfl_xor(sq, m);
    }
    __shared__ float ss[4], ssq[4];
    const int w = t >> 6;
    if ((t & 63) == 0) { ss[w] = s; ssq[w] = sq; }
    __syncthreads();
    s  = ss[0] + ss[1] + ss[2] + ss[3];
    sq = ssq[0] + ssq[1] + ssq[2] + ssq[3];
    const float mu  = s * (1.f / EDIM);
    const float var = sq * (1.f / EDIM) - mu * mu;
    const float rstd = 1.0f / sqrtf(var + 1e-12f);

#pragma unroll
    for (int c = t; c < EDIM; c += 256) {
        out[(size_t)row * EDIM + c] = (x[c] - mu) * rstd * g[c] + be[c];
    }
}

// ---------------------------------------------------------------------------
extern "C" void kernel_launch(void* const* d_in, const int* in_sizes, int n_in,
                              void* d_out, int out_size, void* d_ws, size_t ws_size,
                              hipStream_t stream) {
    const float* hs   = (const float*)d_in[0];
    const float* mask = (const float*)d_in[1];
    const float* Wq   = (const float*)d_in[2];
    const float* bq   = (const float*)d_in[3];
    const float* Wv   = (const float*)d_in[4];
    const float* bv   = (const float*)d_in[5];
    const float* Wo   = (const float*)d_in[6];
    const float* bo   = (const float*)d_in[7];
    const float* g    = (const float*)d_in[8];
    const float* be   = (const float*)d_in[9];

    char* w8 = (char*)d_ws;
    // byte offsets
    unsigned short* Qb   = (unsigned short*)(w8);               //  6,291,456 B
    unsigned short* Vt   = (unsigned short*)(w8 +  6291456);    //  6,291,456 B
    float*          qn   = (float*)        (w8 + 12582912);     //    196,608 B
    unsigned short* AObf = (unsigned short*)(w8 + 12779520);    //  6,291,456 B
    unsigned short* hsb  = (unsigned short*)(w8 + 19070976);    //  6,291,456 B
    unsigned short* Wqvb = (unsigned short*)(w8 + 25362432);    //  2,359,296 B
    unsigned short* Wob  = (unsigned short*)(w8 + 27721728);    //  1,179,648 B
    float*          TMP  = (float*)(w8);                        // alias Qb+Vt (dead)

    precast_kernel<<<dim3(4800),   256, 0, stream>>>(hs, Wq, Wv, Wo, hsb, Wqvb, Wob);
    qv_gemm       <<<dim3(12, 32), 256, 0, stream>>>(hsb, Wqvb, bq, bv, Qb, Vt, qn);
    attn_kernel   <<<dim3(64, 24), 256, 0, stream>>>(Qb, Vt, qn, mask, AObf);
    oproj_gemm    <<<dim3(6, 32),  256, 0, stream>>>(AObf, Wob, bo, hs, TMP);
    ln_kernel     <<<dim3(4096),   256, 0, stream>>>(TMP, g, be, (float*)d_out);
}